// Round 6
// baseline (511.493 us; speedup 1.0000x reference)
//
#include <hip/hip_runtime.h>
#include <math.h>

#define F 64
#define NP 16
#define SCAN_B 1024

// ---------------- CSR build ----------------

__global__ void k_count(const int* __restrict__ dst, int* __restrict__ deg, int nE) {
    int i = blockIdx.x * blockDim.x + threadIdx.x;
    if (i < nE) atomicAdd(&deg[dst[i]], 1);
}

__global__ __launch_bounds__(256) void k_bsum(const int* __restrict__ deg, int* __restrict__ bsum, int n) {
    __shared__ int sd[256];
    int base = blockIdx.x * SCAN_B;
    int s = 0;
    for (int i = threadIdx.x; i < SCAN_B; i += 256) {
        int idx = base + i;
        if (idx < n) s += deg[idx];
    }
    sd[threadIdx.x] = s; __syncthreads();
    for (int off = 128; off; off >>= 1) {
        if (threadIdx.x < off) sd[threadIdx.x] += sd[threadIdx.x + off];
        __syncthreads();
    }
    if (threadIdx.x == 0) bsum[blockIdx.x] = sd[0];
}

__global__ void k_scanb(int* __restrict__ bsum, int nb) {
    int lane = threadIdx.x;  // blockDim.x == 64
    int carry = 0;
    for (int base = 0; base < nb; base += 64) {
        int idx = base + lane;
        int orig = (idx < nb) ? bsum[idx] : 0;
        int v = orig;
        for (int off = 1; off < 64; off <<= 1) {
            int t = __shfl_up(v, off);
            if (lane >= off) v += t;
        }
        if (idx < nb) bsum[idx] = carry + v - orig;  // exclusive
        carry += __shfl(v, 63);
    }
}

__global__ __launch_bounds__(SCAN_B) void k_scanfinal(
    const int* __restrict__ deg, const int* __restrict__ bsum,
    int* __restrict__ rowstart, int* __restrict__ cursor,
    float* __restrict__ invd, int n)
{
    __shared__ int sd[SCAN_B];
    int idx = blockIdx.x * SCAN_B + threadIdx.x;
    int d = (idx < n) ? deg[idx] : 0;
    sd[threadIdx.x] = d; __syncthreads();
    for (int off = 1; off < SCAN_B; off <<= 1) {
        int t = (threadIdx.x >= off) ? sd[threadIdx.x - off] : 0;
        __syncthreads();
        sd[threadIdx.x] += t;
        __syncthreads();
    }
    if (idx < n) {
        int rs = bsum[blockIdx.x] + sd[threadIdx.x] - d;  // exclusive
        rowstart[idx] = rs;
        cursor[idx] = rs;
        invd[idx] = (d > 0) ? 1.0f / (float)d : 0.0f;
    }
}

__global__ void k_fill(const int* __restrict__ src, const int* __restrict__ dst,
                       int* __restrict__ cursor, int* __restrict__ csr, int nE) {
    int i = blockIdx.x * blockDim.x + threadIdx.x;
    if (i < nE) {
        int slot = atomicAdd(&cursor[dst[i]], 1);
        csr[slot] = src[i];
    }
}

// ---------------- gather: agg[n] = mean over neighbors of x[src] ----------------
// one wave per node; 4 lane-groups of 16, float4 row loads, 2 edges in flight.
// Pure: reads x, writes agg (disjoint buffers). Identical to round-4's passing kernel.
__global__ __launch_bounds__(256) void k_gather(
    const float* __restrict__ x, const int* __restrict__ csr,
    const int* __restrict__ rowstart, const int* __restrict__ deg,
    const float* __restrict__ invd, float* __restrict__ agg, int nN)
{
    int wid = (blockIdx.x * blockDim.x + threadIdx.x) >> 6;
    int nW  = (gridDim.x * blockDim.x) >> 6;
    int lane = threadIdx.x & 63;
    int g = lane >> 4, c = lane & 15;
    for (int n = wid; n < nN; n += nW) {
        int rs = rowstart[n], e = rs + deg[n];
        float ax = 0.f, ay = 0.f, az = 0.f, aw = 0.f;
        int i = rs + g;
        while (i + 4 < e) {
            int s0 = csr[i], s1 = csr[i + 4];
            float4 v0 = *(const float4*)(x + (size_t)(unsigned)(s0 * F) + c * 4);
            float4 v1 = *(const float4*)(x + (size_t)(unsigned)(s1 * F) + c * 4);
            ax += v0.x + v1.x; ay += v0.y + v1.y;
            az += v0.z + v1.z; aw += v0.w + v1.w;
            i += 8;
        }
        if (i < e) {
            int s0 = csr[i];
            float4 v0 = *(const float4*)(x + (size_t)(unsigned)(s0 * F) + c * 4);
            ax += v0.x; ay += v0.y; az += v0.z; aw += v0.w;
        }
        ax += __shfl_xor(ax, 16); ay += __shfl_xor(ay, 16);
        az += __shfl_xor(az, 16); aw += __shfl_xor(aw, 16);
        ax += __shfl_xor(ax, 32); ay += __shfl_xor(ay, 32);
        az += __shfl_xor(az, 32); aw += __shfl_xor(aw, 32);
        float iv = invd[n];
        if (lane < 16) {
            float4 r; r.x = ax * iv; r.y = ay * iv; r.z = az * iv; r.w = aw * iv;
            *(float4*)(agg + (size_t)n * F + lane * 4) = r;
        }
    }
}

// ---------------- fused layer: out = relu(x@Ws + agg@Wn + b) ----------------
// one wave per node; lane j owns output column j. Both weight matrices in VGPRs;
// x/agg rows read via wave-uniform float4 broadcast loads. No LDS, no aliasing.
__global__ __launch_bounds__(256) void k_fused1(
    const float* __restrict__ x, const float* __restrict__ agg,
    const float* __restrict__ Ws, const float* __restrict__ Wn,
    const float* __restrict__ b, float* __restrict__ out, int nN)
{
    int lane = threadIdx.x & 63;
    float ws[F], wn[F];
#pragma unroll
    for (int k = 0; k < F; ++k) { ws[k] = Ws[k * F + lane]; wn[k] = Wn[k * F + lane]; }
    float bj = b[lane];
    int wid = (blockIdx.x * blockDim.x + threadIdx.x) >> 6;
    int nW  = (gridDim.x * blockDim.x) >> 6;
    for (int n = wid; n < nN; n += nW) {
        const float4* xr = (const float4*)(x + (size_t)n * F);
        const float4* ar = (const float4*)(agg + (size_t)n * F);
        float a0 = bj, a1 = 0.f, a2 = 0.f, a3 = 0.f;
#pragma unroll
        for (int k4 = 0; k4 < F / 4; ++k4) {
            float4 xv = xr[k4];  // wave-uniform -> hardware broadcast
            float4 av = ar[k4];
            a0 = fmaf(xv.x, ws[4 * k4 + 0], a0); a1 = fmaf(av.x, wn[4 * k4 + 0], a1);
            a2 = fmaf(xv.y, ws[4 * k4 + 1], a2); a3 = fmaf(av.y, wn[4 * k4 + 1], a3);
            a0 = fmaf(xv.z, ws[4 * k4 + 2], a0); a1 = fmaf(av.z, wn[4 * k4 + 2], a1);
            a2 = fmaf(xv.w, ws[4 * k4 + 3], a2); a3 = fmaf(av.w, wn[4 * k4 + 3], a3);
        }
        out[(size_t)n * F + lane] = fmaxf((a0 + a1) + (a2 + a3), 0.f);
    }
}

// ---------------- fused layer 2 + FC + softmax -> d_out directly --------------
// h2 stays in registers (one value per lane). FC: lane (g,c) holds Wfc[16g+t][c]
// (16 regs), pulls h_{16g+t} via shuffle, partial logits reduced with xor16/xor32.
__global__ __launch_bounds__(256) void k_fused2(
    const float* __restrict__ x, const float* __restrict__ agg,
    const float* __restrict__ Ws, const float* __restrict__ Wn,
    const float* __restrict__ b, const float* __restrict__ Wfc,
    const float* __restrict__ bfc, float* __restrict__ out, int nN)
{
    int lane = threadIdx.x & 63;
    int g = lane >> 4, c = lane & 15;
    float ws[F], wn[F], wf[16];
#pragma unroll
    for (int k = 0; k < F; ++k) { ws[k] = Ws[k * F + lane]; wn[k] = Wn[k * F + lane]; }
#pragma unroll
    for (int t = 0; t < 16; ++t) wf[t] = Wfc[(16 * g + t) * NP + c];
    float bj = b[lane], bf = bfc[c];
    int wid = (blockIdx.x * blockDim.x + threadIdx.x) >> 6;
    int nW  = (gridDim.x * blockDim.x) >> 6;
    for (int n = wid; n < nN; n += nW) {
        const float4* xr = (const float4*)(x + (size_t)n * F);
        const float4* ar = (const float4*)(agg + (size_t)n * F);
        float a0 = bj, a1 = 0.f, a2 = 0.f, a3 = 0.f;
#pragma unroll
        for (int k4 = 0; k4 < F / 4; ++k4) {
            float4 xv = xr[k4];
            float4 av = ar[k4];
            a0 = fmaf(xv.x, ws[4 * k4 + 0], a0); a1 = fmaf(av.x, wn[4 * k4 + 0], a1);
            a2 = fmaf(xv.y, ws[4 * k4 + 1], a2); a3 = fmaf(av.y, wn[4 * k4 + 1], a3);
            a0 = fmaf(xv.z, ws[4 * k4 + 2], a0); a1 = fmaf(av.z, wn[4 * k4 + 2], a1);
            a2 = fmaf(xv.w, ws[4 * k4 + 3], a2); a3 = fmaf(av.w, wn[4 * k4 + 3], a3);
        }
        float h = fmaxf((a0 + a1) + (a2 + a3), 0.f);  // h2[lane] for this node
        // FC partial: this lane covers k in [16g, 16g+16) for class c
        float p = 0.f;
#pragma unroll
        for (int t = 0; t < 16; ++t) {
            float hk = __shfl(h, 16 * g + t);
            p = fmaf(hk, wf[t], p);
        }
        // sum the 4 group-partials for each class (lanes {c, c+16, c+32, c+48})
        p += __shfl_xor(p, 16);
        p += __shfl_xor(p, 32);
        float lg = p + bf;
        // softmax over the 16 classes within each 16-lane group
        float m = lg;
        for (int off = 8; off; off >>= 1) m = fmaxf(m, __shfl_xor(m, off, 16));
        float e2 = __expf(lg - m);
        float s = e2;
        for (int off = 8; off; off >>= 1) s += __shfl_xor(s, off, 16);
        if (lane < NP) out[(size_t)n * NP + lane] = e2 / s;
    }
}

extern "C" void kernel_launch(void* const* d_in, const int* in_sizes, int n_in,
                              void* d_out, int out_size, void* d_ws, size_t ws_size,
                              hipStream_t stream) {
    const float* features = (const float*)d_in[0];
    const int*   src      = (const int*)d_in[1];
    const int*   dst      = (const int*)d_in[2];
    const float* Ws1      = (const float*)d_in[3];
    const float* Wn1      = (const float*)d_in[4];
    const float* b1       = (const float*)d_in[5];
    const float* Ws2      = (const float*)d_in[6];
    const float* Wn2      = (const float*)d_in[7];
    const float* b2       = (const float*)d_in[8];
    const float* Wfc      = (const float*)d_in[9];
    const float* bfc      = (const float*)d_in[10];
    float* out = (float*)d_out;

    int nE = in_sizes[1];
    int nN = in_sizes[0] / F;
    int nb = (nN + SCAN_B - 1) / SCAN_B;

    // workspace: deg | rowstart | cursor | bsum(pad) | csr | invd | zbuf | ybuf
    int*   deg      = (int*)d_ws;
    int*   rowstart = deg + nN;
    int*   cursor   = rowstart + nN;
    int*   bsum     = cursor + nN;
    int*   csr      = bsum + ((nb + 255) & ~255);
    float* invd     = (float*)(csr + nE);
    float* zbuf     = invd + nN;
    float* ybuf     = zbuf + (size_t)nN * F;

    hipMemsetAsync(deg, 0, (size_t)nN * sizeof(int), stream);

    // build CSR
    k_count<<<(nE + 255) / 256, 256, 0, stream>>>(dst, deg, nE);
    k_bsum<<<nb, 256, 0, stream>>>(deg, bsum, nN);
    k_scanb<<<1, 64, 0, stream>>>(bsum, nb);
    k_scanfinal<<<nb, SCAN_B, 0, stream>>>(deg, bsum, rowstart, cursor, invd, nN);
    k_fill<<<(nE + 255) / 256, 256, 0, stream>>>(src, dst, cursor, csr, nE);

    // layer 1: ybuf = meanG(features); zbuf = relu(features@Ws1 + ybuf@Wn1 + b1)
    k_gather<<<4096, 256, 0, stream>>>(features, csr, rowstart, deg, invd, ybuf, nN);
    k_fused1<<<2048, 256, 0, stream>>>(features, ybuf, Ws1, Wn1, b1, zbuf, nN);

    // layer 2: ybuf = meanG(zbuf); out = softmax(relu(zbuf@Ws2 + ybuf@Wn2 + b2)@Wfc + bfc)
    k_gather<<<4096, 256, 0, stream>>>(zbuf, csr, rowstart, deg, invd, ybuf, nN);
    k_fused2<<<2048, 256, 0, stream>>>(zbuf, ybuf, Ws2, Wn2, b2, Wfc, bfc, out, nN);
}

// Round 7
// 277.226 us; speedup vs baseline: 1.8450x; 1.8450x over previous
//
#include <hip/hip_runtime.h>
#include <math.h>

#define F 64
#define NP 16
#define SCAN_B 1024

typedef __bf16 bf16x8 __attribute__((ext_vector_type(8)));
typedef float f32x4 __attribute__((ext_vector_type(4)));

__device__ __forceinline__ short f2bf(float v) {
    union { __bf16 b; short s; } u; u.b = (__bf16)v; return u.s;
}
__device__ __forceinline__ float bfbits2f(short s) {
    union { short s; __bf16 b; } u; u.s = s; return (float)u.b;
}

// ---------------- CSR build ----------------

__global__ void k_count(const int* __restrict__ dst, int* __restrict__ deg, int nE) {
    int i = blockIdx.x * blockDim.x + threadIdx.x;
    if (i < nE) atomicAdd(&deg[dst[i]], 1);
}

__global__ __launch_bounds__(256) void k_bsum(const int* __restrict__ deg, int* __restrict__ bsum, int n) {
    __shared__ int sd[256];
    int base = blockIdx.x * SCAN_B;
    int s = 0;
    for (int i = threadIdx.x; i < SCAN_B; i += 256) {
        int idx = base + i;
        if (idx < n) s += deg[idx];
    }
    sd[threadIdx.x] = s; __syncthreads();
    for (int off = 128; off; off >>= 1) {
        if (threadIdx.x < off) sd[threadIdx.x] += sd[threadIdx.x + off];
        __syncthreads();
    }
    if (threadIdx.x == 0) bsum[blockIdx.x] = sd[0];
}

__global__ void k_scanb(int* __restrict__ bsum, int nb) {
    int lane = threadIdx.x;  // blockDim.x == 64
    int carry = 0;
    for (int base = 0; base < nb; base += 64) {
        int idx = base + lane;
        int orig = (idx < nb) ? bsum[idx] : 0;
        int v = orig;
        for (int off = 1; off < 64; off <<= 1) {
            int t = __shfl_up(v, off);
            if (lane >= off) v += t;
        }
        if (idx < nb) bsum[idx] = carry + v - orig;  // exclusive
        carry += __shfl(v, 63);
    }
}

__global__ __launch_bounds__(SCAN_B) void k_scanfinal(
    const int* __restrict__ deg, const int* __restrict__ bsum,
    int* __restrict__ rowstart, int* __restrict__ cursor,
    float* __restrict__ invd, int n)
{
    __shared__ int sd[SCAN_B];
    int idx = blockIdx.x * SCAN_B + threadIdx.x;
    int d = (idx < n) ? deg[idx] : 0;
    sd[threadIdx.x] = d; __syncthreads();
    for (int off = 1; off < SCAN_B; off <<= 1) {
        int t = (threadIdx.x >= off) ? sd[threadIdx.x - off] : 0;
        __syncthreads();
        sd[threadIdx.x] += t;
        __syncthreads();
    }
    if (idx < n) {
        int rs = bsum[blockIdx.x] + sd[threadIdx.x] - d;  // exclusive
        rowstart[idx] = rs;
        cursor[idx] = rs;
        invd[idx] = (d > 0) ? 1.0f / (float)d : 0.0f;
    }
}

__global__ void k_fill(const int* __restrict__ src, const int* __restrict__ dst,
                       int* __restrict__ cursor, int* __restrict__ csr, int nE) {
    int i = blockIdx.x * blockDim.x + threadIdx.x;
    if (i < nE) {
        int slot = atomicAdd(&cursor[dst[i]], 1);
        csr[slot] = src[i];
    }
}

// ---------------- gather: agg[n] = mean over neighbors of x[src] ----------------
// one wave per node; 4 lane-groups of 16, float4 row loads (r4/r6 proven kernel)
__global__ __launch_bounds__(256) void k_gather(
    const float* __restrict__ x, const int* __restrict__ csr,
    const int* __restrict__ rowstart, const int* __restrict__ deg,
    const float* __restrict__ invd, float* __restrict__ agg, int nN)
{
    int wid = (blockIdx.x * blockDim.x + threadIdx.x) >> 6;
    int nW  = (gridDim.x * blockDim.x) >> 6;
    int lane = threadIdx.x & 63;
    int g = lane >> 4, c = lane & 15;
    for (int n = wid; n < nN; n += nW) {
        int rs = rowstart[n], e = rs + deg[n];
        float ax = 0.f, ay = 0.f, az = 0.f, aw = 0.f;
        int i = rs + g;
        while (i + 4 < e) {
            int s0 = csr[i], s1 = csr[i + 4];
            float4 v0 = *(const float4*)(x + (size_t)(unsigned)(s0 * F) + c * 4);
            float4 v1 = *(const float4*)(x + (size_t)(unsigned)(s1 * F) + c * 4);
            ax += v0.x + v1.x; ay += v0.y + v1.y;
            az += v0.z + v1.z; aw += v0.w + v1.w;
            i += 8;
        }
        if (i < e) {
            int s0 = csr[i];
            float4 v0 = *(const float4*)(x + (size_t)(unsigned)(s0 * F) + c * 4);
            ax += v0.x; ay += v0.y; az += v0.z; aw += v0.w;
        }
        ax += __shfl_xor(ax, 16); ay += __shfl_xor(ay, 16);
        az += __shfl_xor(az, 16); aw += __shfl_xor(aw, 16);
        ax += __shfl_xor(ax, 32); ay += __shfl_xor(ay, 32);
        az += __shfl_xor(az, 32); aw += __shfl_xor(aw, 32);
        float iv = invd[n];
        if (lane < 16) {
            float4 r; r.x = ax * iv; r.y = ay * iv; r.z = az * iv; r.w = aw * iv;
            *(float4*)(agg + (size_t)n * F + lane * 4) = r;
        }
    }
}

// ---------------- MFMA fused layer: out = relu([x|agg]@[Ws;Wn] + b) -----------
// One block = 16 nodes. Split-bf16 (hi+lo) staging of x/agg keeps ~f32 accuracy.
// Wave w computes output cols [16w,16w+16). DO_FC: +FC(16x16x64 MFMA)+softmax.
template<bool DO_FC>
__global__ __launch_bounds__(256) void k_layer(
    const float* __restrict__ x, const float* __restrict__ agg,
    const float* __restrict__ Ws, const float* __restrict__ Wn,
    const float* __restrict__ bias,
    const float* __restrict__ Wfc, const float* __restrict__ bfc,
    float* __restrict__ out, int nN)
{
    __shared__ short lds_hi[16][136];   // 16 nodes x 128 K (X|A) bf16, pad->16B-aligned rows
    __shared__ short lds_lo[16][136];
    __shared__ short lds_hb[16][72];    // h tile (bf16) for FC; unused if !DO_FC

    int t = threadIdx.x;
    int w = t >> 6, l = t & 63;
    int base = blockIdx.x * 16;

    // ---- stage tile: convert f32 -> (hi, lo) bf16, K-concat [X | A] ----
    {
        int r = t >> 4, c4 = t & 15;    // node-in-tile, float4 chunk
        int node = base + r;
        float4 xv = make_float4(0.f, 0.f, 0.f, 0.f);
        float4 av = make_float4(0.f, 0.f, 0.f, 0.f);
        if (node < nN) {
            xv = *(const float4*)(x + (size_t)node * F + c4 * 4);
            av = *(const float4*)(agg + (size_t)node * F + c4 * 4);
        }
        const float* xp = &xv.x; const float* ap = &av.x;
        short hx[4], lx[4], ha[4], la[4];
#pragma unroll
        for (int jj = 0; jj < 4; ++jj) {
            float v = xp[jj]; short h = f2bf(v); hx[jj] = h; lx[jj] = f2bf(v - bfbits2f(h));
            v = ap[jj]; h = f2bf(v); ha[jj] = h; la[jj] = f2bf(v - bfbits2f(h));
        }
        *(short4*)&lds_hi[r][c4 * 4]      = make_short4(hx[0], hx[1], hx[2], hx[3]);
        *(short4*)&lds_lo[r][c4 * 4]      = make_short4(lx[0], lx[1], lx[2], lx[3]);
        *(short4*)&lds_hi[r][64 + c4 * 4] = make_short4(ha[0], ha[1], ha[2], ha[3]);
        *(short4*)&lds_lo[r][64 + c4 * 4] = make_short4(la[0], la[1], la[2], la[3]);
    }

    // ---- B fragments: Wcat[k][col] bf16, k=(l>>4)*8+e within each ktile ----
    int kg = l >> 4;                // 0..3
    int col = w * 16 + (l & 15);    // output column this lane contributes to
    bf16x8 bw[4];
#pragma unroll
    for (int kt = 0; kt < 4; ++kt)
#pragma unroll
        for (int e = 0; e < 8; ++e) {
            int k = kt * 32 + kg * 8 + e;
            float wv = (k < F) ? Ws[k * F + col] : Wn[(k - F) * F + col];
            bw[kt][e] = (__bf16)wv;
        }

    __syncthreads();

    // ---- MFMA: acc = X_hi@W + X_lo@W over 4 K-tiles ----
    int m = l & 15;                 // A-fragment row (node-in-tile)
    f32x4 acc = {0.f, 0.f, 0.f, 0.f};
#pragma unroll
    for (int kt = 0; kt < 4; ++kt) {
        bf16x8 ah = *(const bf16x8*)&lds_hi[m][kt * 32 + kg * 8];
        bf16x8 al = *(const bf16x8*)&lds_lo[m][kt * 32 + kg * 8];
        acc = __builtin_amdgcn_mfma_f32_16x16x32_bf16(ah, bw[kt], acc, 0, 0, 0);
        acc = __builtin_amdgcn_mfma_f32_16x16x32_bf16(al, bw[kt], acc, 0, 0, 0);
    }

    // C/D layout: col = lane&15 (matches `col`), row = (lane>>4)*4 + reg
    float bj = bias[col];
    if constexpr (!DO_FC) {
#pragma unroll
        for (int i = 0; i < 4; ++i) {
            int node = base + (l >> 4) * 4 + i;
            if (node < nN)
                out[(size_t)node * F + col] = fmaxf(acc[i] + bj, 0.f);
        }
    } else {
        // h tile -> LDS (bf16); then FC = h(16x64) @ Wfc(64x16) via 2 MFMA by wave 0
#pragma unroll
        for (int i = 0; i < 4; ++i) {
            int nit = (l >> 4) * 4 + i;
            lds_hb[nit][col] = f2bf(fmaxf(acc[i] + bj, 0.f));
        }
        __syncthreads();
        if (w == 0) {
            bf16x8 wf[2];
#pragma unroll
            for (int kt = 0; kt < 2; ++kt)
#pragma unroll
                for (int e = 0; e < 8; ++e) {
                    int k = kt * 32 + kg * 8 + e;
                    wf[kt][e] = (__bf16)Wfc[k * NP + (l & 15)];
                }
            f32x4 lacc = {0.f, 0.f, 0.f, 0.f};
#pragma unroll
            for (int kt = 0; kt < 2; ++kt) {
                bf16x8 hfrag = *(const bf16x8*)&lds_hb[m][kt * 32 + kg * 8];
                lacc = __builtin_amdgcn_mfma_f32_16x16x32_bf16(hfrag, wf[kt], lacc, 0, 0, 0);
            }
            float bf = bfc[l & 15];
#pragma unroll
            for (int i = 0; i < 4; ++i) {
                float lg = lacc[i] + bf;
                float mm = lg;
                for (int off = 8; off; off >>= 1) mm = fmaxf(mm, __shfl_xor(mm, off, 16));
                float e2 = __expf(lg - mm);
                float ss = e2;
                for (int off = 8; off; off >>= 1) ss += __shfl_xor(ss, off, 16);
                int node = base + (l >> 4) * 4 + i;
                if (node < nN) out[(size_t)node * NP + (l & 15)] = e2 / ss;
            }
        }
    }
}

extern "C" void kernel_launch(void* const* d_in, const int* in_sizes, int n_in,
                              void* d_out, int out_size, void* d_ws, size_t ws_size,
                              hipStream_t stream) {
    const float* features = (const float*)d_in[0];
    const int*   src      = (const int*)d_in[1];
    const int*   dst      = (const int*)d_in[2];
    const float* Ws1      = (const float*)d_in[3];
    const float* Wn1      = (const float*)d_in[4];
    const float* b1       = (const float*)d_in[5];
    const float* Ws2      = (const float*)d_in[6];
    const float* Wn2      = (const float*)d_in[7];
    const float* b2       = (const float*)d_in[8];
    const float* Wfc      = (const float*)d_in[9];
    const float* bfc      = (const float*)d_in[10];
    float* out = (float*)d_out;

    int nE = in_sizes[1];
    int nN = in_sizes[0] / F;
    int nb = (nN + SCAN_B - 1) / SCAN_B;
    int nTiles = (nN + 15) / 16;

    // workspace: deg | rowstart | cursor | bsum(pad) | csr | invd | zbuf | ybuf
    int*   deg      = (int*)d_ws;
    int*   rowstart = deg + nN;
    int*   cursor   = rowstart + nN;
    int*   bsum     = cursor + nN;
    int*   csr      = bsum + ((nb + 255) & ~255);
    float* invd     = (float*)(csr + nE);
    float* zbuf     = invd + nN;
    float* ybuf     = zbuf + (size_t)nN * F;

    hipMemsetAsync(deg, 0, (size_t)nN * sizeof(int), stream);

    // build CSR
    k_count<<<(nE + 255) / 256, 256, 0, stream>>>(dst, deg, nE);
    k_bsum<<<nb, 256, 0, stream>>>(deg, bsum, nN);
    k_scanb<<<1, 64, 0, stream>>>(bsum, nb);
    k_scanfinal<<<nb, SCAN_B, 0, stream>>>(deg, bsum, rowstart, cursor, invd, nN);
    k_fill<<<(nE + 255) / 256, 256, 0, stream>>>(src, dst, cursor, csr, nE);

    // layer 1: ybuf = meanG(features); zbuf = relu([features|ybuf]@[Ws1;Wn1]+b1)
    k_gather<<<4096, 256, 0, stream>>>(features, csr, rowstart, deg, invd, ybuf, nN);
    k_layer<false><<<nTiles, 256, 0, stream>>>(features, ybuf, Ws1, Wn1, b1,
                                               nullptr, nullptr, zbuf, nN);

    // layer 2 + FC + softmax -> d_out
    k_gather<<<4096, 256, 0, stream>>>(zbuf, csr, rowstart, deg, invd, ybuf, nN);
    k_layer<true><<<nTiles, 256, 0, stream>>>(zbuf, ybuf, Ws2, Wn2, b2,
                                              Wfc, bfc, out, nN);
}

// Round 8
// 175.886 us; speedup vs baseline: 2.9081x; 1.5762x over previous
//
#include <hip/hip_runtime.h>
#include <math.h>

#define F 64
#define NP 16
#define BK_SHIFT 9
#define BK_SIZE 512
#define MAXB 256
#define CHUNK 8192

typedef __bf16 bf16x8 __attribute__((ext_vector_type(8)));
typedef float f32x4 __attribute__((ext_vector_type(4)));

__device__ __forceinline__ short f2bf(float v) {
    union { __bf16 b; short s; } u; u.b = (__bf16)v; return u.s;
}
__device__ __forceinline__ float bfbits2f(short s) {
    union { short s; __bf16 b; } u; u.s = s; return (float)u.b;
}

// ---------------- bucketed CSR build (all per-edge atomics in LDS) ----------------

// A: histogram of edges per 512-node bucket (LDS-privatized)
__global__ __launch_bounds__(1024) void k_bhist(const int* __restrict__ dst,
                                                int* __restrict__ bcnt, int nE) {
    __shared__ int h[MAXB];
    for (int i = threadIdx.x; i < MAXB; i += 1024) h[i] = 0;
    __syncthreads();
    for (int i = blockIdx.x * blockDim.x + threadIdx.x; i < nE; i += gridDim.x * blockDim.x)
        atomicAdd(&h[dst[i] >> BK_SHIFT], 1);
    __syncthreads();
    for (int i = threadIdx.x; i < MAXB; i += 1024)
        if (h[i]) atomicAdd(&bcnt[i], h[i]);
}

// A2: exclusive scan of the 256 bucket counts; init global bucket cursors
__global__ __launch_bounds__(MAXB) void k_bscan(const int* __restrict__ bcnt,
                                                int* __restrict__ bbase, int* __restrict__ bcur) {
    __shared__ int sc[MAXB];
    int t = threadIdx.x;
    int v = bcnt[t];
    sc[t] = v; __syncthreads();
    for (int off = 1; off < MAXB; off <<= 1) {
        int u = (t >= off) ? sc[t - off] : 0;
        __syncthreads();
        sc[t] += u;
        __syncthreads();
    }
    bbase[t] = sc[t] - v;
    bcur[t]  = sc[t] - v;
}

// B: partition edges into bucket-major order; block-aggregated reservation
__global__ __launch_bounds__(1024) void k_bucket(const int* __restrict__ src,
                                                 const int* __restrict__ dst,
                                                 int* __restrict__ bcur,
                                                 int2* __restrict__ ebuf, int nE) {
    __shared__ int h[MAXB];
    __shared__ int base[MAXB];
    int t = threadIdx.x;
    int lo = blockIdx.x * CHUNK, hi = min(lo + CHUNK, nE);
    for (int i = t; i < MAXB; i += 1024) h[i] = 0;
    __syncthreads();
    for (int i = lo + t; i < hi; i += 1024) atomicAdd(&h[dst[i] >> BK_SHIFT], 1);
    __syncthreads();
    for (int i = t; i < MAXB; i += 1024) {
        base[i] = h[i] ? atomicAdd(&bcur[i], h[i]) : 0;
        h[i] = 0;  // reuse as intra-block rank counter
    }
    __syncthreads();
    for (int i = lo + t; i < hi; i += 1024) {
        int d = dst[i], b = d >> BK_SHIFT;
        int r = atomicAdd(&h[b], 1);
        ebuf[base[b] + r] = make_int2(src[i], d);
    }
}

// C: per-bucket local CSR: LDS count -> LDS scan -> LDS-cursor fill
__global__ __launch_bounds__(BK_SIZE) void k_bcsr(const int2* __restrict__ ebuf,
                                                  const int* __restrict__ bbase,
                                                  const int* __restrict__ bcnt,
                                                  int* __restrict__ rowstart,
                                                  int* __restrict__ deg,
                                                  int* __restrict__ csr,
                                                  float* __restrict__ invd, int nN) {
    __shared__ int cnt[BK_SIZE];
    __shared__ int sc[BK_SIZE];
    __shared__ int cur[BK_SIZE];
    int b = blockIdx.x, t = threadIdx.x;
    int nodeBase = b << BK_SHIFT;
    int ebase = bbase[b], ecnt = bcnt[b];
    cnt[t] = 0; __syncthreads();
    for (int i = t; i < ecnt; i += BK_SIZE)
        atomicAdd(&cnt[ebuf[ebase + i].y - nodeBase], 1);
    __syncthreads();
    int c = cnt[t];
    sc[t] = c; __syncthreads();
    for (int off = 1; off < BK_SIZE; off <<= 1) {
        int u = (t >= off) ? sc[t - off] : 0;
        __syncthreads();
        sc[t] += u;
        __syncthreads();
    }
    int ex = sc[t] - c;
    cur[t] = ex;
    int node = nodeBase + t;
    if (node < nN) {
        rowstart[node] = ebase + ex;
        deg[node] = c;
        invd[node] = c ? 1.0f / (float)c : 0.0f;
    }
    __syncthreads();
    for (int i = t; i < ecnt; i += BK_SIZE) {
        int2 e = ebuf[ebase + i];
        int r = atomicAdd(&cur[e.y - nodeBase], 1);
        csr[ebase + r] = e.x;
    }
}

// ---------------- gather: agg[n] = mean over neighbors of x[src] ----------------
// one wave per node; 4 lane-groups of 16, float4 row loads (r4/r6/r7 proven kernel)
__global__ __launch_bounds__(256) void k_gather(
    const float* __restrict__ x, const int* __restrict__ csr,
    const int* __restrict__ rowstart, const int* __restrict__ deg,
    const float* __restrict__ invd, float* __restrict__ agg, int nN)
{
    int wid = (blockIdx.x * blockDim.x + threadIdx.x) >> 6;
    int nW  = (gridDim.x * blockDim.x) >> 6;
    int lane = threadIdx.x & 63;
    int g = lane >> 4, c = lane & 15;
    for (int n = wid; n < nN; n += nW) {
        int rs = rowstart[n], e = rs + deg[n];
        float ax = 0.f, ay = 0.f, az = 0.f, aw = 0.f;
        int i = rs + g;
        while (i + 4 < e) {
            int s0 = csr[i], s1 = csr[i + 4];
            float4 v0 = *(const float4*)(x + (size_t)(unsigned)(s0 * F) + c * 4);
            float4 v1 = *(const float4*)(x + (size_t)(unsigned)(s1 * F) + c * 4);
            ax += v0.x + v1.x; ay += v0.y + v1.y;
            az += v0.z + v1.z; aw += v0.w + v1.w;
            i += 8;
        }
        if (i < e) {
            int s0 = csr[i];
            float4 v0 = *(const float4*)(x + (size_t)(unsigned)(s0 * F) + c * 4);
            ax += v0.x; ay += v0.y; az += v0.z; aw += v0.w;
        }
        ax += __shfl_xor(ax, 16); ay += __shfl_xor(ay, 16);
        az += __shfl_xor(az, 16); aw += __shfl_xor(aw, 16);
        ax += __shfl_xor(ax, 32); ay += __shfl_xor(ay, 32);
        az += __shfl_xor(az, 32); aw += __shfl_xor(aw, 32);
        float iv = invd[n];
        if (lane < 16) {
            float4 r; r.x = ax * iv; r.y = ay * iv; r.z = az * iv; r.w = aw * iv;
            *(float4*)(agg + (size_t)n * F + lane * 4) = r;
        }
    }
}

// ---------------- MFMA fused layer: out = relu([x|agg]@[Ws;Wn] + b) -----------
// One block = 16 nodes. Split-bf16 (hi+lo) staging of x/agg keeps ~f32 accuracy.
// Wave w computes output cols [16w,16w+16). DO_FC: +FC(16x16x32 MFMA x2)+softmax.
template<bool DO_FC>
__global__ __launch_bounds__(256) void k_layer(
    const float* __restrict__ x, const float* __restrict__ agg,
    const float* __restrict__ Ws, const float* __restrict__ Wn,
    const float* __restrict__ bias,
    const float* __restrict__ Wfc, const float* __restrict__ bfc,
    float* __restrict__ out, int nN)
{
    __shared__ short lds_hi[16][136];
    __shared__ short lds_lo[16][136];
    __shared__ short lds_hb[16][72];

    int t = threadIdx.x;
    int w = t >> 6, l = t & 63;
    int base = blockIdx.x * 16;

    {
        int r = t >> 4, c4 = t & 15;
        int node = base + r;
        float4 xv = make_float4(0.f, 0.f, 0.f, 0.f);
        float4 av = make_float4(0.f, 0.f, 0.f, 0.f);
        if (node < nN) {
            xv = *(const float4*)(x + (size_t)node * F + c4 * 4);
            av = *(const float4*)(agg + (size_t)node * F + c4 * 4);
        }
        const float* xp = &xv.x; const float* ap = &av.x;
        short hx[4], lx[4], ha[4], la[4];
#pragma unroll
        for (int jj = 0; jj < 4; ++jj) {
            float v = xp[jj]; short h = f2bf(v); hx[jj] = h; lx[jj] = f2bf(v - bfbits2f(h));
            v = ap[jj]; h = f2bf(v); ha[jj] = h; la[jj] = f2bf(v - bfbits2f(h));
        }
        *(short4*)&lds_hi[r][c4 * 4]      = make_short4(hx[0], hx[1], hx[2], hx[3]);
        *(short4*)&lds_lo[r][c4 * 4]      = make_short4(lx[0], lx[1], lx[2], lx[3]);
        *(short4*)&lds_hi[r][64 + c4 * 4] = make_short4(ha[0], ha[1], ha[2], ha[3]);
        *(short4*)&lds_lo[r][64 + c4 * 4] = make_short4(la[0], la[1], la[2], la[3]);
    }

    int kg = l >> 4;
    int col = w * 16 + (l & 15);
    bf16x8 bw[4];
#pragma unroll
    for (int kt = 0; kt < 4; ++kt)
#pragma unroll
        for (int e = 0; e < 8; ++e) {
            int k = kt * 32 + kg * 8 + e;
            float wv = (k < F) ? Ws[k * F + col] : Wn[(k - F) * F + col];
            bw[kt][e] = (__bf16)wv;
        }

    __syncthreads();

    int m = l & 15;
    f32x4 acc = {0.f, 0.f, 0.f, 0.f};
#pragma unroll
    for (int kt = 0; kt < 4; ++kt) {
        bf16x8 ah = *(const bf16x8*)&lds_hi[m][kt * 32 + kg * 8];
        bf16x8 al = *(const bf16x8*)&lds_lo[m][kt * 32 + kg * 8];
        acc = __builtin_amdgcn_mfma_f32_16x16x32_bf16(ah, bw[kt], acc, 0, 0, 0);
        acc = __builtin_amdgcn_mfma_f32_16x16x32_bf16(al, bw[kt], acc, 0, 0, 0);
    }

    float bj = bias[col];
    if constexpr (!DO_FC) {
#pragma unroll
        for (int i = 0; i < 4; ++i) {
            int node = base + (l >> 4) * 4 + i;
            if (node < nN)
                out[(size_t)node * F + col] = fmaxf(acc[i] + bj, 0.f);
        }
    } else {
#pragma unroll
        for (int i = 0; i < 4; ++i) {
            int nit = (l >> 4) * 4 + i;
            lds_hb[nit][col] = f2bf(fmaxf(acc[i] + bj, 0.f));
        }
        __syncthreads();
        if (w == 0) {
            bf16x8 wf[2];
#pragma unroll
            for (int kt = 0; kt < 2; ++kt)
#pragma unroll
                for (int e = 0; e < 8; ++e) {
                    int k = kt * 32 + kg * 8 + e;
                    wf[kt][e] = (__bf16)Wfc[k * NP + (l & 15)];
                }
            f32x4 lacc = {0.f, 0.f, 0.f, 0.f};
#pragma unroll
            for (int kt = 0; kt < 2; ++kt) {
                bf16x8 hfrag = *(const bf16x8*)&lds_hb[m][kt * 32 + kg * 8];
                lacc = __builtin_amdgcn_mfma_f32_16x16x32_bf16(hfrag, wf[kt], lacc, 0, 0, 0);
            }
            float bf = bfc[l & 15];
#pragma unroll
            for (int i = 0; i < 4; ++i) {
                float lg = lacc[i] + bf;
                float mm = lg;
                for (int off = 8; off; off >>= 1) mm = fmaxf(mm, __shfl_xor(mm, off, 16));
                float e2 = __expf(lg - mm);
                float ss = e2;
                for (int off = 8; off; off >>= 1) ss += __shfl_xor(ss, off, 16);
                int node = base + (l >> 4) * 4 + i;
                if (node < nN) out[(size_t)node * NP + (l & 15)] = e2 / ss;
            }
        }
    }
}

extern "C" void kernel_launch(void* const* d_in, const int* in_sizes, int n_in,
                              void* d_out, int out_size, void* d_ws, size_t ws_size,
                              hipStream_t stream) {
    const float* features = (const float*)d_in[0];
    const int*   src      = (const int*)d_in[1];
    const int*   dst      = (const int*)d_in[2];
    const float* Ws1      = (const float*)d_in[3];
    const float* Wn1      = (const float*)d_in[4];
    const float* b1       = (const float*)d_in[5];
    const float* Ws2      = (const float*)d_in[6];
    const float* Wn2      = (const float*)d_in[7];
    const float* b2       = (const float*)d_in[8];
    const float* Wfc      = (const float*)d_in[9];
    const float* bfc      = (const float*)d_in[10];
    float* out = (float*)d_out;

    int nE = in_sizes[1];
    int nN = in_sizes[0] / F;
    int nB = (nN + BK_SIZE - 1) >> BK_SHIFT;   // 196 for 100k nodes (<= MAXB)
    int nTiles = (nN + 15) / 16;

    // workspace: ebuf(int2) | bcnt | bbase | bcur | rowstart | deg | csr | invd | zbuf | ybuf
    int2*  ebuf     = (int2*)d_ws;
    int*   bcnt     = (int*)(ebuf + nE);
    int*   bbase    = bcnt + MAXB;
    int*   bcur     = bbase + MAXB;
    int*   rowstart = bcur + MAXB;
    int*   deg      = rowstart + nN;
    int*   csr      = deg + nN;
    float* invd     = (float*)(csr + nE);
    float* zbuf     = invd + nN;
    float* ybuf     = zbuf + (size_t)nN * F;

    hipMemsetAsync(bcnt, 0, MAXB * sizeof(int), stream);

    // bucketed CSR build
    k_bhist<<<128, 1024, 0, stream>>>(dst, bcnt, nE);
    k_bscan<<<1, MAXB, 0, stream>>>(bcnt, bbase, bcur);
    k_bucket<<<(nE + CHUNK - 1) / CHUNK, 1024, 0, stream>>>(src, dst, bcur, ebuf, nE);
    k_bcsr<<<nB, BK_SIZE, 0, stream>>>(ebuf, bbase, bcnt, rowstart, deg, csr, invd, nN);

    // layer 1: ybuf = meanG(features); zbuf = relu([features|ybuf]@[Ws1;Wn1]+b1)
    k_gather<<<4096, 256, 0, stream>>>(features, csr, rowstart, deg, invd, ybuf, nN);
    k_layer<false><<<nTiles, 256, 0, stream>>>(features, ybuf, Ws1, Wn1, b1,
                                               nullptr, nullptr, zbuf, nN);

    // layer 2 + FC + softmax -> d_out
    k_gather<<<4096, 256, 0, stream>>>(zbuf, csr, rowstart, deg, invd, ybuf, nN);
    k_layer<true><<<nTiles, 256, 0, stream>>>(zbuf, ybuf, Ws2, Wn2, b2,
                                              Wfc, bfc, out, nN);
}

// Round 9
// 166.817 us; speedup vs baseline: 3.0662x; 1.0544x over previous
//
#include <hip/hip_runtime.h>
#include <math.h>

#define F 64
#define NP 16
#define BK_SHIFT 9
#define BK_SIZE 512
#define MAXB 256
#define CHUNK 8192

typedef __bf16 bf16x8 __attribute__((ext_vector_type(8)));
typedef float f32x4 __attribute__((ext_vector_type(4)));

__device__ __forceinline__ short f2bf(float v) {
    union { __bf16 b; short s; } u; u.b = (__bf16)v; return u.s;
}
__device__ __forceinline__ float bfbits2f(short s) {
    union { short s; __bf16 b; } u; u.s = s; return (float)u.b;
}
__device__ __forceinline__ float bf2f(unsigned short u) {
    union { unsigned u; float f; } t; t.u = ((unsigned)u) << 16; return t.f;
}

// ---------------- bucketed CSR build (all per-edge atomics in LDS) ----------------

__global__ __launch_bounds__(1024) void k_bhist(const int* __restrict__ dst,
                                                int* __restrict__ bcnt, int nE) {
    __shared__ int h[MAXB];
    for (int i = threadIdx.x; i < MAXB; i += 1024) h[i] = 0;
    __syncthreads();
    for (int i = blockIdx.x * blockDim.x + threadIdx.x; i < nE; i += gridDim.x * blockDim.x)
        atomicAdd(&h[dst[i] >> BK_SHIFT], 1);
    __syncthreads();
    for (int i = threadIdx.x; i < MAXB; i += 1024)
        if (h[i]) atomicAdd(&bcnt[i], h[i]);
}

__global__ __launch_bounds__(MAXB) void k_bscan(const int* __restrict__ bcnt,
                                                int* __restrict__ bbase, int* __restrict__ bcur) {
    __shared__ int sc[MAXB];
    int t = threadIdx.x;
    int v = bcnt[t];
    sc[t] = v; __syncthreads();
    for (int off = 1; off < MAXB; off <<= 1) {
        int u = (t >= off) ? sc[t - off] : 0;
        __syncthreads();
        sc[t] += u;
        __syncthreads();
    }
    bbase[t] = sc[t] - v;
    bcur[t]  = sc[t] - v;
}

__global__ __launch_bounds__(1024) void k_bucket(const int* __restrict__ src,
                                                 const int* __restrict__ dst,
                                                 int* __restrict__ bcur,
                                                 int2* __restrict__ ebuf, int nE) {
    __shared__ int h[MAXB];
    __shared__ int base[MAXB];
    int t = threadIdx.x;
    int lo = blockIdx.x * CHUNK, hi = min(lo + CHUNK, nE);
    for (int i = t; i < MAXB; i += 1024) h[i] = 0;
    __syncthreads();
    for (int i = lo + t; i < hi; i += 1024) atomicAdd(&h[dst[i] >> BK_SHIFT], 1);
    __syncthreads();
    for (int i = t; i < MAXB; i += 1024) {
        base[i] = h[i] ? atomicAdd(&bcur[i], h[i]) : 0;
        h[i] = 0;
    }
    __syncthreads();
    for (int i = lo + t; i < hi; i += 1024) {
        int d = dst[i], b = d >> BK_SHIFT;
        int r = atomicAdd(&h[b], 1);
        ebuf[base[b] + r] = make_int2(src[i], d);
    }
}

__global__ __launch_bounds__(BK_SIZE) void k_bcsr(const int2* __restrict__ ebuf,
                                                  const int* __restrict__ bbase,
                                                  const int* __restrict__ bcnt,
                                                  int* __restrict__ rowstart,
                                                  int* __restrict__ deg,
                                                  int* __restrict__ csr,
                                                  float* __restrict__ invd, int nN) {
    __shared__ int cnt[BK_SIZE];
    __shared__ int sc[BK_SIZE];
    __shared__ int cur[BK_SIZE];
    int b = blockIdx.x, t = threadIdx.x;
    int nodeBase = b << BK_SHIFT;
    int ebase = bbase[b], ecnt = bcnt[b];
    cnt[t] = 0; __syncthreads();
    for (int i = t; i < ecnt; i += BK_SIZE)
        atomicAdd(&cnt[ebuf[ebase + i].y - nodeBase], 1);
    __syncthreads();
    int c = cnt[t];
    sc[t] = c; __syncthreads();
    for (int off = 1; off < BK_SIZE; off <<= 1) {
        int u = (t >= off) ? sc[t - off] : 0;
        __syncthreads();
        sc[t] += u;
        __syncthreads();
    }
    int ex = sc[t] - c;
    cur[t] = ex;
    int node = nodeBase + t;
    if (node < nN) {
        rowstart[node] = ebase + ex;
        deg[node] = c;
        invd[node] = c ? 1.0f / (float)c : 0.0f;
    }
    __syncthreads();
    for (int i = t; i < ecnt; i += BK_SIZE) {
        int2 e = ebuf[ebase + i];
        int r = atomicAdd(&cur[e.y - nodeBase], 1);
        csr[ebase + r] = e.x;
    }
}

// ---------------- f32 -> bf16 plane copy ----------------
__global__ __launch_bounds__(256) void k_tobf(const float* __restrict__ in,
                                              unsigned short* __restrict__ outp, int n) {
    int i = (blockIdx.x * blockDim.x + threadIdx.x) * 4;
    if (i < n) {
        float4 v = *(const float4*)(in + i);
        short4 r;
        r.x = f2bf(v.x); r.y = f2bf(v.y); r.z = f2bf(v.z); r.w = f2bf(v.w);
        *(short4*)(outp + i) = r;
    }
}

// ---------------- gather (bf16 rows): agg[n] = mean over neighbors of xb[src] ----
// one wave per node; 4 lane-groups of 16, short4 (8B) row loads, 2 edges in flight
__global__ __launch_bounds__(256) void k_gather(
    const unsigned short* __restrict__ xb, const int* __restrict__ csr,
    const int* __restrict__ rowstart, const int* __restrict__ deg,
    const float* __restrict__ invd, float* __restrict__ agg, int nN)
{
    int wid = (blockIdx.x * blockDim.x + threadIdx.x) >> 6;
    int nW  = (gridDim.x * blockDim.x) >> 6;
    int lane = threadIdx.x & 63;
    int g = lane >> 4, c = lane & 15;
    for (int n = wid; n < nN; n += nW) {
        int rs = rowstart[n], e = rs + deg[n];
        float ax = 0.f, ay = 0.f, az = 0.f, aw = 0.f;
        int i = rs + g;
        while (i + 4 < e) {
            int s0 = csr[i], s1 = csr[i + 4];
            ushort4 v0 = *(const ushort4*)(xb + (size_t)(unsigned)(s0 * F) + c * 4);
            ushort4 v1 = *(const ushort4*)(xb + (size_t)(unsigned)(s1 * F) + c * 4);
            ax += bf2f(v0.x) + bf2f(v1.x); ay += bf2f(v0.y) + bf2f(v1.y);
            az += bf2f(v0.z) + bf2f(v1.z); aw += bf2f(v0.w) + bf2f(v1.w);
            i += 8;
        }
        if (i < e) {
            int s0 = csr[i];
            ushort4 v0 = *(const ushort4*)(xb + (size_t)(unsigned)(s0 * F) + c * 4);
            ax += bf2f(v0.x); ay += bf2f(v0.y); az += bf2f(v0.z); aw += bf2f(v0.w);
        }
        ax += __shfl_xor(ax, 16); ay += __shfl_xor(ay, 16);
        az += __shfl_xor(az, 16); aw += __shfl_xor(aw, 16);
        ax += __shfl_xor(ax, 32); ay += __shfl_xor(ay, 32);
        az += __shfl_xor(az, 32); aw += __shfl_xor(aw, 32);
        float iv = invd[n];
        if (lane < 16) {
            float4 r; r.x = ax * iv; r.y = ay * iv; r.z = az * iv; r.w = aw * iv;
            *(float4*)(agg + (size_t)n * F + lane * 4) = r;
        }
    }
}

// ---------------- MFMA fused layer: out = relu([x|agg]@[Ws;Wn] + b) -----------
// One block = 16 nodes. x comes either as f32 (XBF=false) or as hi/lo bf16
// planes (XBF=true, exact to ~2^-17). Layer output is written as hi/lo planes
// (DO_FC=false) or as softmax(FC(h)) to d_out (DO_FC=true).
template<bool DO_FC, bool XBF>
__global__ __launch_bounds__(256) void k_layer(
    const float* __restrict__ xf,
    const unsigned short* __restrict__ xhi, const unsigned short* __restrict__ xlo,
    const float* __restrict__ agg,
    const float* __restrict__ Ws, const float* __restrict__ Wn,
    const float* __restrict__ bias,
    const float* __restrict__ Wfc, const float* __restrict__ bfc,
    unsigned short* __restrict__ outhi, unsigned short* __restrict__ outlo,
    float* __restrict__ out, int nN)
{
    __shared__ short lds_hi[16][136];
    __shared__ short lds_lo[16][136];
    __shared__ short lds_hb[16][72];

    int t = threadIdx.x;
    int w = t >> 6, l = t & 63;
    int base = blockIdx.x * 16;

    {
        int r = t >> 4, c4 = t & 15;
        int node = base + r;
        // x part (K 0..63)
        if (XBF) {
            short4 hx = make_short4(0, 0, 0, 0), lx = make_short4(0, 0, 0, 0);
            if (node < nN) {
                hx = *(const short4*)(xhi + (size_t)node * F + c4 * 4);
                lx = *(const short4*)(xlo + (size_t)node * F + c4 * 4);
            }
            *(short4*)&lds_hi[r][c4 * 4] = hx;
            *(short4*)&lds_lo[r][c4 * 4] = lx;
        } else {
            float4 xv = make_float4(0.f, 0.f, 0.f, 0.f);
            if (node < nN) xv = *(const float4*)(xf + (size_t)node * F + c4 * 4);
            const float* xp = &xv.x;
            short hx[4], lx[4];
#pragma unroll
            for (int jj = 0; jj < 4; ++jj) {
                float v = xp[jj]; short h = f2bf(v);
                hx[jj] = h; lx[jj] = f2bf(v - bfbits2f(h));
            }
            *(short4*)&lds_hi[r][c4 * 4] = make_short4(hx[0], hx[1], hx[2], hx[3]);
            *(short4*)&lds_lo[r][c4 * 4] = make_short4(lx[0], lx[1], lx[2], lx[3]);
        }
        // agg part (K 64..127), f32 -> hi/lo
        float4 av = make_float4(0.f, 0.f, 0.f, 0.f);
        if (node < nN) av = *(const float4*)(agg + (size_t)node * F + c4 * 4);
        const float* ap = &av.x;
        short ha[4], la[4];
#pragma unroll
        for (int jj = 0; jj < 4; ++jj) {
            float v = ap[jj]; short h = f2bf(v);
            ha[jj] = h; la[jj] = f2bf(v - bfbits2f(h));
        }
        *(short4*)&lds_hi[r][64 + c4 * 4] = make_short4(ha[0], ha[1], ha[2], ha[3]);
        *(short4*)&lds_lo[r][64 + c4 * 4] = make_short4(la[0], la[1], la[2], la[3]);
    }

    int kg = l >> 4;
    int col = w * 16 + (l & 15);
    bf16x8 bw[4];
#pragma unroll
    for (int kt = 0; kt < 4; ++kt)
#pragma unroll
        for (int e = 0; e < 8; ++e) {
            int k = kt * 32 + kg * 8 + e;
            float wv = (k < F) ? Ws[k * F + col] : Wn[(k - F) * F + col];
            bw[kt][e] = (__bf16)wv;
        }

    __syncthreads();

    int m = l & 15;
    f32x4 acc = {0.f, 0.f, 0.f, 0.f};
#pragma unroll
    for (int kt = 0; kt < 4; ++kt) {
        bf16x8 ah = *(const bf16x8*)&lds_hi[m][kt * 32 + kg * 8];
        bf16x8 al = *(const bf16x8*)&lds_lo[m][kt * 32 + kg * 8];
        acc = __builtin_amdgcn_mfma_f32_16x16x32_bf16(ah, bw[kt], acc, 0, 0, 0);
        acc = __builtin_amdgcn_mfma_f32_16x16x32_bf16(al, bw[kt], acc, 0, 0, 0);
    }

    float bj = bias[col];
    if constexpr (!DO_FC) {
#pragma unroll
        for (int i = 0; i < 4; ++i) {
            int node = base + (l >> 4) * 4 + i;
            if (node < nN) {
                float v = fmaxf(acc[i] + bj, 0.f);
                short h = f2bf(v);
                outhi[(size_t)node * F + col] = (unsigned short)h;
                outlo[(size_t)node * F + col] = (unsigned short)f2bf(v - bfbits2f(h));
            }
        }
    } else {
#pragma unroll
        for (int i = 0; i < 4; ++i) {
            int nit = (l >> 4) * 4 + i;
            lds_hb[nit][col] = f2bf(fmaxf(acc[i] + bj, 0.f));
        }
        __syncthreads();
        if (w == 0) {
            bf16x8 wf[2];
#pragma unroll
            for (int kt = 0; kt < 2; ++kt)
#pragma unroll
                for (int e = 0; e < 8; ++e) {
                    int k = kt * 32 + kg * 8 + e;
                    wf[kt][e] = (__bf16)Wfc[k * NP + (l & 15)];
                }
            f32x4 lacc = {0.f, 0.f, 0.f, 0.f};
#pragma unroll
            for (int kt = 0; kt < 2; ++kt) {
                bf16x8 hfrag = *(const bf16x8*)&lds_hb[m][kt * 32 + kg * 8];
                lacc = __builtin_amdgcn_mfma_f32_16x16x32_bf16(hfrag, wf[kt], lacc, 0, 0, 0);
            }
            float bf = bfc[l & 15];
#pragma unroll
            for (int i = 0; i < 4; ++i) {
                float lg = lacc[i] + bf;
                float mm = lg;
                for (int off = 8; off; off >>= 1) mm = fmaxf(mm, __shfl_xor(mm, off, 16));
                float e2 = __expf(lg - mm);
                float ss = e2;
                for (int off = 8; off; off >>= 1) ss += __shfl_xor(ss, off, 16);
                int node = base + (l >> 4) * 4 + i;
                if (node < nN) out[(size_t)node * NP + (l & 15)] = e2 / ss;
            }
        }
    }
}

extern "C" void kernel_launch(void* const* d_in, const int* in_sizes, int n_in,
                              void* d_out, int out_size, void* d_ws, size_t ws_size,
                              hipStream_t stream) {
    const float* features = (const float*)d_in[0];
    const int*   src      = (const int*)d_in[1];
    const int*   dst      = (const int*)d_in[2];
    const float* Ws1      = (const float*)d_in[3];
    const float* Wn1      = (const float*)d_in[4];
    const float* b1       = (const float*)d_in[5];
    const float* Ws2      = (const float*)d_in[6];
    const float* Wn2      = (const float*)d_in[7];
    const float* b2       = (const float*)d_in[8];
    const float* Wfc      = (const float*)d_in[9];
    const float* bfc      = (const float*)d_in[10];
    float* out = (float*)d_out;

    int nE = in_sizes[1];
    int nN = in_sizes[0] / F;
    int nB = (nN + BK_SIZE - 1) >> BK_SHIFT;
    int nTiles = (nN + 15) / 16;

    // workspace: ebuf(int2) | bcnt | bbase | bcur | rowstart | deg | csr | invd |
    //            xhi(u16) | zhi(u16) | zlo(u16) | ybuf(f32)
    int2*  ebuf     = (int2*)d_ws;
    int*   bcnt     = (int*)(ebuf + nE);
    int*   bbase    = bcnt + MAXB;
    int*   bcur     = bbase + MAXB;
    int*   rowstart = bcur + MAXB;
    int*   deg      = rowstart + nN;
    int*   csr      = deg + nN;
    float* invd     = (float*)(csr + nE);
    unsigned short* xhi = (unsigned short*)(invd + nN);
    unsigned short* zhi = xhi + (size_t)nN * F;
    unsigned short* zlo = zhi + (size_t)nN * F;
    float* ybuf     = (float*)(zlo + (size_t)nN * F);

    hipMemsetAsync(bcnt, 0, MAXB * sizeof(int), stream);

    // bucketed CSR build
    k_bhist<<<128, 1024, 0, stream>>>(dst, bcnt, nE);
    k_bscan<<<1, MAXB, 0, stream>>>(bcnt, bbase, bcur);
    k_bucket<<<(nE + CHUNK - 1) / CHUNK, 1024, 0, stream>>>(src, dst, bcur, ebuf, nE);
    k_bcsr<<<nB, BK_SIZE, 0, stream>>>(ebuf, bbase, bcnt, rowstart, deg, csr, invd, nN);

    // bf16 copy of features for the gather path
    k_tobf<<<(nN * F / 4 + 255) / 256, 256, 0, stream>>>(features, xhi, nN * F);

    // layer 1: ybuf = meanG(xhi); zhi/zlo = relu([features|ybuf]@[Ws1;Wn1]+b1)
    k_gather<<<4096, 256, 0, stream>>>(xhi, csr, rowstart, deg, invd, ybuf, nN);
    k_layer<false, false><<<nTiles, 256, 0, stream>>>(
        features, nullptr, nullptr, ybuf, Ws1, Wn1, b1, nullptr, nullptr,
        zhi, zlo, nullptr, nN);

    // layer 2 + FC + softmax -> d_out
    k_gather<<<4096, 256, 0, stream>>>(zhi, csr, rowstart, deg, invd, ybuf, nN);
    k_layer<true, true><<<nTiles, 256, 0, stream>>>(
        nullptr, zhi, zlo, ybuf, Ws2, Wn2, b2, Wfc, bfc,
        nullptr, nullptr, out, nN);
}